// Round 7
// baseline (347.945 us; speedup 1.0000x reference)
//
#include <hip/hip_runtime.h>
#include <math.h>

#define N_NODES 10000
#define MPAD    10112   // 79 * 128
#define D_IN    1000
#define KPAD_IN 1024
#define D0      256
#define D1      128
#define NPAD_OUT 1024
#define NEG_SLOPE 0.2f

typedef __attribute__((ext_vector_type(8))) short short8;
typedef __attribute__((ext_vector_type(4))) float f32x4;

__device__ __forceinline__ ushort f2bf(float f) {
  union { float f; unsigned u; } c; c.f = f;
  unsigned r = c.u + 0x7FFF + ((c.u >> 16) & 1);   // RNE
  return (ushort)(r >> 16);
}
__device__ __forceinline__ float bf2f(ushort b) {
  union { unsigned u; float f; } c; c.u = ((unsigned)b) << 16;
  return c.f;
}

// ---------------- CSR build ----------------

__global__ void count_kernel(const int* __restrict__ idx, int E, int n, int* __restrict__ counts) {
  int k = blockIdx.x * blockDim.x + threadIdx.x;
  int tot = E + n;
  if (k >= tot) return;
  int dst = (k < E) ? idx[E + k] : (k - E);   // self-loops appended
  atomicAdd(&counts[dst], 1);
}

__global__ void scan_kernel(const int* __restrict__ counts, int* __restrict__ offsets,
                            int* __restrict__ cursors, int n) {
  __shared__ int tsum[1024];
  int tid = threadIdx.x;
  int per = (n + 1023) / 1024;
  int start = tid * per;
  int end = start + per; if (end > n) end = n;
  int s = 0;
  for (int i = start; i < end; i++) s += counts[i];
  tsum[tid] = s;
  __syncthreads();
  for (int off = 1; off < 1024; off <<= 1) {
    int v = (tid >= off) ? tsum[tid - off] : 0;
    __syncthreads();
    if (tid >= off) tsum[tid] += v;
    __syncthreads();
  }
  int run = (tid == 0) ? 0 : tsum[tid - 1];
  for (int i = start; i < end; i++) {
    offsets[i] = run; cursors[i] = run;
    run += counts[i];
  }
  if (tid == 1023) offsets[n] = tsum[1023];
}

__global__ void scatter_kernel(const int* __restrict__ idx, int E, int n,
                               int* __restrict__ cursors, int* __restrict__ srcs) {
  int k = blockIdx.x * blockDim.x + threadIdx.x;
  int tot = E + n;
  if (k >= tot) return;
  int src, dst;
  if (k < E) { src = idx[k]; dst = idx[E + k]; }
  else       { src = k - E;  dst = src; }
  int pos = atomicAdd(&cursors[dst], 1);
  srcs[pos] = src;
}

// ---------------- input / weight prep ----------------

__global__ void conv_x_kernel(const float* __restrict__ x, ushort* __restrict__ xb) {
  int idx = blockIdx.x * blockDim.x + threadIdx.x;   // slot of 4 elems
  int r = idx >> 8, k4 = (idx & 255) * 4;
  ushort4 o = {0, 0, 0, 0};
  if (r < N_NODES && k4 < D_IN) {                    // D_IN divisible by 4
    float4 v = *(const float4*)(x + (size_t)r * D_IN + k4);
    o.x = f2bf(v.x); o.y = f2bf(v.y); o.z = f2bf(v.z); o.w = f2bf(v.w);
  }
  *(ushort4*)(xb + (size_t)idx * 4) = o;
}

// all weight transposes + bias concats in one launch
#define T_WPI   (256 * 1024)
#define T_W1    (256 * 256)
#define T_W2    (512 * 128)
#define T_WPO   (1024 * 256)
#define OFF_W1  T_WPI
#define OFF_W2  (OFF_W1 + T_W1)
#define OFF_WPO (OFF_W2 + T_W2)
#define OFF_B   (OFF_WPO + T_WPO)
#define T_ALL   (OFF_B + 768)

__global__ void wprep_all(const float* __restrict__ Wpi,
                          const float* __restrict__ Wl1, const float* __restrict__ Wr1,
                          const float* __restrict__ Wl2, const float* __restrict__ Wr2,
                          const float* __restrict__ Wpo,
                          const float* __restrict__ bl1, const float* __restrict__ br1,
                          const float* __restrict__ bl2, const float* __restrict__ br2,
                          ushort* __restrict__ Wpi_t, ushort* __restrict__ W1cat,
                          ushort* __restrict__ W2cat, ushort* __restrict__ Wpo_t,
                          float* __restrict__ bcat1, float* __restrict__ bcat2) {
  int idx = blockIdx.x * 256 + threadIdx.x;
  if (idx >= T_ALL) return;
  if (idx < OFF_W1) {                       // Wpi_t [256][1024] <- Wpi [1000][256]
    int n = idx >> 10, k = idx & 1023;
    Wpi_t[idx] = f2bf((k < 1000) ? Wpi[(size_t)k * 256 + n] : 0.f);
  } else if (idx < OFF_W2) {                // W1cat [256][256] <- Wl1|Wr1 [256][128]
    int q = idx - OFF_W1, n = q >> 8, k = q & 255;
    float v = (n < 128) ? Wl1[k * 128 + n] : Wr1[k * 128 + (n - 128)];
    W1cat[q] = f2bf(v);
  } else if (idx < OFF_WPO) {               // W2cat [512][128] <- Wl2|Wr2 [128][256]
    int q = idx - OFF_W2, n = q >> 7, k = q & 127;
    float v = (n < 256) ? Wl2[k * 256 + n] : Wr2[k * 256 + (n - 256)];
    W2cat[q] = f2bf(v);
  } else if (idx < OFF_B) {                 // Wpo_t [1024][256] <- Wpo [256][1000]
    int q = idx - OFF_WPO, n = q >> 8, k = q & 255;
    Wpo_t[q] = f2bf((n < 1000) ? Wpo[(size_t)k * 1000 + n] : 0.f);
  } else {
    int q = idx - OFF_B;
    if (q < 128)      bcat1[q] = bl1[q];
    else if (q < 256) bcat1[q] = br1[q - 128];
    else if (q < 512) bcat2[q - 256] = bl2[q - 256];
    else              bcat2[q - 256] = br2[q - 512];
  }
}

// ---------------- bf16 MFMA GEMM ----------------
// C[M,N] = A[M,K](bf16, lda) @ Bt[N,K](bf16, ldb)^T + bias
// MODE 0: f32 out guarded, MODE 1: bf16 out (pad rows zeroed),
// MODE 2: split — col<ldp -> bf16 Cb, col>=ldp -> f32 Cf.

template<int MODE>
__launch_bounds__(256)
__global__ void gemm_mfma(const ushort* __restrict__ A, int lda,
                          const ushort* __restrict__ Bt, int ldb,
                          const float* __restrict__ bias,
                          float* __restrict__ Cf, ushort* __restrict__ Cb, int ldp,
                          int M_valid, int N_valid, int K) {
  constexpr int BK = 32;
  __shared__ ushort As[128 * BK];
  __shared__ ushort Bs[128 * BK];
  const int tid  = threadIdx.x;
  const int lane = tid & 63, wave = tid >> 6;
  const int wr = wave >> 1, wc = wave & 1;
  const int bm = blockIdx.y * 128, bn = blockIdx.x * 128;
  const int r16 = lane & 15, kb = lane >> 4;

  f32x4 acc[4][4] = {};

  const int srow = tid >> 2;
  const int scol = (tid & 3) * 8;    // ushort elems (16B)
  const ushort* Ag0 = A  + (size_t)(bm + srow) * lda + scol;
  const ushort* Ag1 = A  + (size_t)(bm + 64 + srow) * lda + scol;
  const ushort* Bg0 = Bt + (size_t)(bn + srow) * ldb + scol;
  const ushort* Bg1 = Bt + (size_t)(bn + 64 + srow) * ldb + scol;

  for (int k0 = 0; k0 < K; k0 += BK) {
    __builtin_amdgcn_global_load_lds((const __attribute__((address_space(1))) void*)(Ag0 + k0),
                                     (__attribute__((address_space(3))) void*)(As + tid * 8), 16, 0, 0);
    __builtin_amdgcn_global_load_lds((const __attribute__((address_space(1))) void*)(Ag1 + k0),
                                     (__attribute__((address_space(3))) void*)(As + 2048 + tid * 8), 16, 0, 0);
    __builtin_amdgcn_global_load_lds((const __attribute__((address_space(1))) void*)(Bg0 + k0),
                                     (__attribute__((address_space(3))) void*)(Bs + tid * 8), 16, 0, 0);
    __builtin_amdgcn_global_load_lds((const __attribute__((address_space(1))) void*)(Bg1 + k0),
                                     (__attribute__((address_space(3))) void*)(Bs + 2048 + tid * 8), 16, 0, 0);
    __syncthreads();

    short8 af[4], bfr[4];
    #pragma unroll
    for (int mi = 0; mi < 4; mi++)
      af[mi] = *(const short8*)(As + ((wr * 64 + mi * 16 + r16) * BK + kb * 8));
    #pragma unroll
    for (int ni = 0; ni < 4; ni++)
      bfr[ni] = *(const short8*)(Bs + ((wc * 64 + ni * 16 + r16) * BK + kb * 8));
    #pragma unroll
    for (int mi = 0; mi < 4; mi++)
      #pragma unroll
      for (int ni = 0; ni < 4; ni++)
        acc[mi][ni] = __builtin_amdgcn_mfma_f32_16x16x32_bf16(af[mi], bfr[ni], acc[mi][ni], 0, 0, 0);
    __syncthreads();
  }

  #pragma unroll
  for (int mi = 0; mi < 4; mi++) {
    const int row = bm + wr * 64 + mi * 16 + (lane >> 4) * 4;
    #pragma unroll
    for (int ni = 0; ni < 4; ni++) {
      const int col = bn + wc * 64 + ni * 16 + r16;
      const float bv = (col < N_valid) ? bias[col] : 0.f;
      #pragma unroll
      for (int r = 0; r < 4; r++) {
        const int gr = row + r;
        const float val = acc[mi][ni][r] + bv;
        if constexpr (MODE == 0) {
          if (gr < M_valid && col < N_valid) Cf[(size_t)gr * ldp + col] = val;
        } else if constexpr (MODE == 1) {
          Cb[(size_t)gr * ldp + col] = f2bf(gr < M_valid ? val : 0.f);
        } else {
          if (col < ldp) Cb[(size_t)gr * ldp + col] = f2bf(val);          // xl (bf16 gather table)
          else           Cf[(size_t)gr * ldp + (col - ldp)] = val;        // xr (f32)
        }
      }
    }
  }
}

// ---------------- fused GATv2: split-K flash softmax, one BLOCK (4 waves) per dst ----------------
// Each wave runs online softmax over a strided quarter of the node's edges (serial chain
// cut 4x), then an LDS merge combines partials exactly (flash split-K merge).

template<int D>
__launch_bounds__(256)
__global__ void gat_fused(const ushort* __restrict__ xlb, const float* __restrict__ xrf,
                          const float* __restrict__ att, const float* __restrict__ bias,
                          const int* __restrict__ offsets, const int* __restrict__ srcs,
                          float* __restrict__ out_f32, ushort* __restrict__ out_bf16,
                          int n_valid) {
  constexpr int EPL = D / 64;     // dims per lane
  const int v    = blockIdx.x;
  const int tid  = threadIdx.x;
  const int lane = tid & 63;
  const int wave = tid >> 6;
  const int d0   = lane * EPL;

  if (v >= n_valid) {             // pad rows -> zero bf16 row
    if (out_bf16 && tid < D) out_bf16[(size_t)v * D + tid] = 0;
    return;
  }

  __shared__ float m_s[4];
  __shared__ float s_s[4];
  __shared__ float buf[4][D];

  float rv[EPL], av[EPL], acc[EPL];
  #pragma unroll
  for (int d = 0; d < EPL; d++) {
    rv[d]  = xrf[(size_t)v * D + d0 + d];
    av[d]  = att[d0 + d];
    acc[d] = 0.f;
  }

  const int beg = offsets[v], end = offsets[v + 1];
  float m = -INFINITY, s = 0.f;

  int k = beg + wave;
  ushort xnxt[EPL];
  if (k < end) {
    const int u0 = srcs[k];
    if constexpr (EPL == 4) *(ushort4*)xnxt = *(const ushort4*)(xlb + (size_t)u0 * D + d0);
    else                    *(ushort2*)xnxt = *(const ushort2*)(xlb + (size_t)u0 * D + d0);
  }

  for (; k < end; k += 4) {
    ushort xcur[EPL];
    #pragma unroll
    for (int d = 0; d < EPL; d++) xcur[d] = xnxt[d];

    const int kn = k + 4;
    if (kn < end) {                 // prefetch next edge in this wave's stride
      const int un = srcs[kn];
      if constexpr (EPL == 4) *(ushort4*)xnxt = *(const ushort4*)(xlb + (size_t)un * D + d0);
      else                    *(ushort2*)xnxt = *(const ushort2*)(xlb + (size_t)un * D + d0);
    }

    float xv[EPL], p = 0.f;
    #pragma unroll
    for (int d = 0; d < EPL; d++) {
      xv[d] = bf2f(xcur[d]);
      float t = xv[d] + rv[d];
      t = fmaxf(t, NEG_SLOPE * t);           // leaky_relu (slope 0.2 > 0)
      p = fmaf(t, av[d], p);
    }
    #pragma unroll
    for (int off = 32; off > 0; off >>= 1) p += __shfl_xor(p, off);

    const float m2   = fmaxf(m, p);
    const float cold = __expf(m - m2);       // first edge: exp(-inf) = 0
    const float w    = __expf(p - m2);
    s = s * cold + w;
    #pragma unroll
    for (int d = 0; d < EPL; d++) acc[d] = fmaf(acc[d], cold, w * xv[d]);
    m = m2;
  }

  // ---- split-K merge across the 4 waves ----
  if (lane == 0) m_s[wave] = m;
  __syncthreads();
  const float M = fmaxf(fmaxf(m_s[0], m_s[1]), fmaxf(m_s[2], m_s[3]));  // finite (>=1 edge)
  const float c = __expf(m - M);            // 0 for empty partials (m = -inf)
  if (lane == 0) s_s[wave] = s * c;
  #pragma unroll
  for (int d = 0; d < EPL; d++) buf[wave][d0 + d] = acc[d] * c;
  __syncthreads();

  if (tid < D) {
    const float stot = s_s[0] + s_s[1] + s_s[2] + s_s[3];
    const float val = (buf[0][tid] + buf[1][tid] + buf[2][tid] + buf[3][tid]) / stot + bias[tid];
    if (out_f32)  out_f32[(size_t)v * D + tid] = val;
    if (out_bf16) out_bf16[(size_t)v * D + tid] = f2bf(val);
  }
}

// ---------------- launch ----------------

extern "C" void kernel_launch(void* const* d_in, const int* in_sizes, int n_in,
                              void* d_out, int out_size, void* d_ws, size_t ws_size,
                              hipStream_t stream) {
  const float* x     = (const float*)d_in[0];
  const int*   eidx  = (const int*)d_in[1];
  const float* Wpi   = (const float*)d_in[2];
  const float* bpi   = (const float*)d_in[3];
  const float* Wl1   = (const float*)d_in[4];
  const float* bl1   = (const float*)d_in[5];
  const float* Wr1   = (const float*)d_in[6];
  const float* br1   = (const float*)d_in[7];
  const float* att1  = (const float*)d_in[8];
  const float* bias1 = (const float*)d_in[9];
  const float* Wl2   = (const float*)d_in[10];
  const float* bl2   = (const float*)d_in[11];
  const float* Wr2   = (const float*)d_in[12];
  const float* br2   = (const float*)d_in[13];
  const float* att2  = (const float*)d_in[14];
  const float* bias2 = (const float*)d_in[15];
  const float* Wpo   = (const float*)d_in[16];
  const float* bpo   = (const float*)d_in[17];

  const int E    = in_sizes[1] / 2;
  const int n    = N_NODES;
  const int Etot = E + n;

  float* out_xhat = (float*)d_out;
  float* out_z    = (float*)d_out + (size_t)N_NODES * D_IN;

  // workspace carve-up
  char* wp = (char*)d_ws;
  auto alloc = [&](size_t bytes) { char* p = wp; wp += (bytes + 255) & ~(size_t)255; return p; };
  char* regionA = (char*)alloc((size_t)MPAD * KPAD_IN * 2);   // xb -> {xr1f,xl1b} -> {xr2f,xl2b}
  ushort* hb_db = (ushort*)alloc((size_t)MPAD * D0 * 2);      // hb then db
  ushort* zb    = (ushort*)alloc((size_t)MPAD * D1 * 2);
  int* counts  = (int*)alloc((size_t)n * 4);
  int* offsets = (int*)alloc((size_t)(n + 1) * 4);
  int* cursors = (int*)alloc((size_t)n * 4);
  int* srcs    = (int*)alloc((size_t)Etot * 4);
  ushort* Wpi_t = (ushort*)alloc((size_t)T_WPI * 2);
  ushort* W1cat = (ushort*)alloc((size_t)T_W1 * 2);
  ushort* W2cat = (ushort*)alloc((size_t)T_W2 * 2);
  ushort* Wpo_t = (ushort*)alloc((size_t)T_WPO * 2);
  float*  bcat1 = (float*)alloc(256 * 4);
  float*  bcat2 = (float*)alloc(512 * 4);

  ushort* xb   = (ushort*)regionA;
  // layer1 intermediates (alias regionA; xb dead by then)
  float*  xr1f = (float*)regionA;                                  // [MPAD][128] f32
  ushort* xl1b = (ushort*)(regionA + 8 * 1024 * 1024);             // [MPAD][128] bf16
  // layer2 intermediates (alias regionA; layer1 dead by then)
  float*  xr2f = (float*)regionA;                                  // [MPAD][256] f32
  ushort* xl2b = (ushort*)(regionA + 12 * 1024 * 1024);            // [MPAD][256] bf16
  ushort* hb   = hb_db;
  ushort* db   = hb_db;

  // CSR
  hipMemsetAsync(counts, 0, (size_t)n * 4, stream);
  const int tb = 256;
  count_kernel<<<(Etot + tb - 1) / tb, tb, 0, stream>>>(eidx, E, n, counts);
  scan_kernel<<<1, 1024, 0, stream>>>(counts, offsets, cursors, n);
  scatter_kernel<<<(Etot + tb - 1) / tb, tb, 0, stream>>>(eidx, E, n, cursors, srcs);

  // prep
  conv_x_kernel<<<MPAD, 256, 0, stream>>>(x, xb);
  wprep_all<<<(T_ALL + 255) / 256, 256, 0, stream>>>(
      Wpi, Wl1, Wr1, Wl2, Wr2, Wpo, bl1, br1, bl2, br2,
      Wpi_t, W1cat, W2cat, Wpo_t, bcat1, bcat2);

  // h = x @ Wpi + bpi  (bf16 out, pad rows zeroed)
  gemm_mfma<1><<<dim3(D0 / 128, MPAD / 128), 256, 0, stream>>>(
      xb, KPAD_IN, Wpi_t, KPAD_IN, bpi, nullptr, hb, D0, N_NODES, D0, KPAD_IN);
  // [xl1(bf16)|xr1(f32)] = h @ [Wl1|Wr1] + [bl1|br1]  (split epilogue, NL=128)
  gemm_mfma<2><<<dim3(256 / 128, MPAD / 128), 256, 0, stream>>>(
      hb, D0, W1cat, D0, bcat1, xr1f, xl1b, D1, N_NODES, 256, D0);
  // GAT1 (fused, block per node) -> out_z (f32) + zb (bf16 padded)
  gat_fused<D1><<<MPAD, 256, 0, stream>>>(xl1b, xr1f, att1, bias1,
                                          offsets, srcs, out_z, zb, N_NODES);
  // [xl2(bf16)|xr2(f32)] = z @ [Wl2|Wr2] + [bl2|br2]  (split epilogue, NL=256)
  gemm_mfma<2><<<dim3(512 / 128, MPAD / 128), 256, 0, stream>>>(
      zb, D1, W2cat, D1, bcat2, xr2f, xl2b, D0, N_NODES, 512, D1);
  // GAT2 (fused, block per node) -> db (bf16 padded)
  gat_fused<D0><<<MPAD, 256, 0, stream>>>(xl2b, xr2f, att2, bias2,
                                          offsets, srcs, nullptr, db, N_NODES);
  // x_hat = d @ Wpo + bpo  (f32 out, guarded)
  gemm_mfma<0><<<dim3(NPAD_OUT / 128, MPAD / 128), 256, 0, stream>>>(
      db, D0, Wpo_t, D0, bpo, out_xhat, nullptr, D_IN, N_NODES, D_IN, D0);
}

// Round 8
// 322.339 us; speedup vs baseline: 1.0794x; 1.0794x over previous
//
#include <hip/hip_runtime.h>
#include <math.h>

#define N_NODES 10000
#define MPAD    10112   // 158 * 64
#define D_IN    1000
#define KPAD_IN 1024
#define D0      256
#define D1      128
#define NPAD_OUT 1024
#define NEG_SLOPE 0.2f

typedef __attribute__((ext_vector_type(8))) short short8;
typedef __attribute__((ext_vector_type(4))) float f32x4;

__device__ __forceinline__ ushort f2bf(float f) {
  union { float f; unsigned u; } c; c.f = f;
  unsigned r = c.u + 0x7FFF + ((c.u >> 16) & 1);   // RNE
  return (ushort)(r >> 16);
}
__device__ __forceinline__ float bf2f(ushort b) {
  union { unsigned u; float f; } c; c.u = ((unsigned)b) << 16;
  return c.f;
}

// ---------------- CSR build ----------------

__global__ void count_kernel(const int* __restrict__ idx, int E, int n, int* __restrict__ counts) {
  int k = blockIdx.x * blockDim.x + threadIdx.x;
  int tot = E + n;
  if (k >= tot) return;
  int dst = (k < E) ? idx[E + k] : (k - E);   // self-loops appended
  atomicAdd(&counts[dst], 1);
}

__global__ void scan_kernel(const int* __restrict__ counts, int* __restrict__ offsets,
                            int* __restrict__ cursors, int n) {
  __shared__ int tsum[1024];
  int tid = threadIdx.x;
  int per = (n + 1023) / 1024;
  int start = tid * per;
  int end = start + per; if (end > n) end = n;
  int s = 0;
  for (int i = start; i < end; i++) s += counts[i];
  tsum[tid] = s;
  __syncthreads();
  for (int off = 1; off < 1024; off <<= 1) {
    int v = (tid >= off) ? tsum[tid - off] : 0;
    __syncthreads();
    if (tid >= off) tsum[tid] += v;
    __syncthreads();
  }
  int run = (tid == 0) ? 0 : tsum[tid - 1];
  for (int i = start; i < end; i++) {
    offsets[i] = run; cursors[i] = run;
    run += counts[i];
  }
  if (tid == 1023) offsets[n] = tsum[1023];
}

__global__ void scatter_kernel(const int* __restrict__ idx, int E, int n,
                               int* __restrict__ cursors, int* __restrict__ srcs) {
  int k = blockIdx.x * blockDim.x + threadIdx.x;
  int tot = E + n;
  if (k >= tot) return;
  int src, dst;
  if (k < E) { src = idx[k]; dst = idx[E + k]; }
  else       { src = k - E;  dst = src; }
  int pos = atomicAdd(&cursors[dst], 1);
  srcs[pos] = src;
}

// ---------------- fused prep: conv_x + all weight transposes + biases + zero counts ----------------

#define T_WPI   (256 * 1024)
#define T_W1    (256 * 256)
#define T_W2    (512 * 128)
#define T_WPO   (1024 * 256)
#define OFF_W1  T_WPI
#define OFF_W2  (OFF_W1 + T_W1)
#define OFF_WPO (OFF_W2 + T_W2)
#define OFF_B   (OFF_WPO + T_WPO)
#define T_ALL   (OFF_B + 768)
#define CONV_T  (MPAD * 256)         // threads, 4 elems each
#define PREP_T  (CONV_T + T_ALL + N_NODES)

__global__ void prep_all(const float* __restrict__ x, ushort* __restrict__ xb,
                         const float* __restrict__ Wpi,
                         const float* __restrict__ Wl1, const float* __restrict__ Wr1,
                         const float* __restrict__ Wl2, const float* __restrict__ Wr2,
                         const float* __restrict__ Wpo,
                         const float* __restrict__ bl1, const float* __restrict__ br1,
                         const float* __restrict__ bl2, const float* __restrict__ br2,
                         ushort* __restrict__ Wpi_t, ushort* __restrict__ W1cat,
                         ushort* __restrict__ W2cat, ushort* __restrict__ Wpo_t,
                         float* __restrict__ bcat1, float* __restrict__ bcat2,
                         int* __restrict__ counts) {
  int idx = blockIdx.x * 256 + threadIdx.x;
  if (idx < CONV_T) {                       // xb[r][k]: bf16(x) zero-padded, 4 elems/thread
    int r = idx >> 8, k4 = (idx & 255) * 4;
    ushort4 o = {0, 0, 0, 0};
    if (r < N_NODES && k4 < D_IN) {
      float4 v = *(const float4*)(x + (size_t)r * D_IN + k4);
      o.x = f2bf(v.x); o.y = f2bf(v.y); o.z = f2bf(v.z); o.w = f2bf(v.w);
    }
    *(ushort4*)(xb + (size_t)idx * 4) = o;
    return;
  }
  int j = idx - CONV_T;
  if (j < OFF_W1) {                         // Wpi_t [256][1024] <- Wpi [1000][256]
    int n = j >> 10, k = j & 1023;
    Wpi_t[j] = f2bf((k < 1000) ? Wpi[(size_t)k * 256 + n] : 0.f);
  } else if (j < OFF_W2) {                  // W1cat [256][256] <- Wl1|Wr1 [256][128]
    int q = j - OFF_W1, n = q >> 8, k = q & 255;
    float v = (n < 128) ? Wl1[k * 128 + n] : Wr1[k * 128 + (n - 128)];
    W1cat[q] = f2bf(v);
  } else if (j < OFF_WPO) {                 // W2cat [512][128] <- Wl2|Wr2 [128][256]
    int q = j - OFF_W2, n = q >> 7, k = q & 127;
    float v = (n < 256) ? Wl2[k * 256 + n] : Wr2[k * 256 + (n - 256)];
    W2cat[q] = f2bf(v);
  } else if (j < OFF_B) {                   // Wpo_t [1024][256] <- Wpo [256][1000]
    int q = j - OFF_WPO, n = q >> 8, k = q & 255;
    Wpo_t[q] = f2bf((n < 1000) ? Wpo[(size_t)k * 1000 + n] : 0.f);
  } else if (j < T_ALL) {
    int q = j - OFF_B;
    if (q < 128)      bcat1[q] = bl1[q];
    else if (q < 256) bcat1[q] = br1[q - 128];
    else if (q < 512) bcat2[q - 256] = bl2[q - 256];
    else              bcat2[q - 256] = br2[q - 512];
  } else {
    int q = j - T_ALL;
    if (q < N_NODES) counts[q] = 0;
  }
}

// ---------------- bf16 MFMA GEMM, 64x64 tile ----------------
// C[M,N] = A[M,K](bf16, lda) @ Bt[N,K](bf16, ldb)^T + bias
// 64x64 tile, BK=32, 4 waves (2x2, each 32x32), 16x16x32 MFMA, global_load_lds staging.
// MODE 0: f32 out guarded, MODE 1: bf16 out (pad rows zeroed),
// MODE 2: split — col<ldp -> bf16 Cb, col>=ldp -> f32 Cf.

template<int MODE>
__launch_bounds__(256)
__global__ void gemm_mfma(const ushort* __restrict__ A, int lda,
                          const ushort* __restrict__ Bt, int ldb,
                          const float* __restrict__ bias,
                          float* __restrict__ Cf, ushort* __restrict__ Cb, int ldp,
                          int M_valid, int N_valid, int K) {
  constexpr int BK = 32;
  __shared__ ushort As[64 * BK];   // 4 KB
  __shared__ ushort Bs[64 * BK];
  const int tid  = threadIdx.x;
  const int lane = tid & 63, wave = tid >> 6;
  const int wr = wave >> 1, wc = wave & 1;
  const int bm = blockIdx.y * 64, bn = blockIdx.x * 64;
  const int r16 = lane & 15, kb = lane >> 4;

  f32x4 acc[2][2] = {};

  const int srow = tid >> 2;          // 0..63
  const int scol = (tid & 3) * 8;     // ushort elems (16B)
  const ushort* Ag = A  + (size_t)(bm + srow) * lda + scol;
  const ushort* Bg = Bt + (size_t)(bn + srow) * ldb + scol;

  for (int k0 = 0; k0 < K; k0 += BK) {
    __builtin_amdgcn_global_load_lds((const __attribute__((address_space(1))) void*)(Ag + k0),
                                     (__attribute__((address_space(3))) void*)(As + tid * 8), 16, 0, 0);
    __builtin_amdgcn_global_load_lds((const __attribute__((address_space(1))) void*)(Bg + k0),
                                     (__attribute__((address_space(3))) void*)(Bs + tid * 8), 16, 0, 0);
    __syncthreads();

    short8 af[2], bfr[2];
    #pragma unroll
    for (int mi = 0; mi < 2; mi++)
      af[mi] = *(const short8*)(As + ((wr * 32 + mi * 16 + r16) * BK + kb * 8));
    #pragma unroll
    for (int ni = 0; ni < 2; ni++)
      bfr[ni] = *(const short8*)(Bs + ((wc * 32 + ni * 16 + r16) * BK + kb * 8));
    #pragma unroll
    for (int mi = 0; mi < 2; mi++)
      #pragma unroll
      for (int ni = 0; ni < 2; ni++)
        acc[mi][ni] = __builtin_amdgcn_mfma_f32_16x16x32_bf16(af[mi], bfr[ni], acc[mi][ni], 0, 0, 0);
    __syncthreads();
  }

  #pragma unroll
  for (int mi = 0; mi < 2; mi++) {
    const int row = bm + wr * 32 + mi * 16 + (lane >> 4) * 4;
    #pragma unroll
    for (int ni = 0; ni < 2; ni++) {
      const int col = bn + wc * 32 + ni * 16 + r16;
      const float bv = (col < N_valid) ? bias[col] : 0.f;
      #pragma unroll
      for (int r = 0; r < 4; r++) {
        const int gr = row + r;
        const float val = acc[mi][ni][r] + bv;
        if constexpr (MODE == 0) {
          if (gr < M_valid && col < N_valid) Cf[(size_t)gr * ldp + col] = val;
        } else if constexpr (MODE == 1) {
          Cb[(size_t)gr * ldp + col] = f2bf(gr < M_valid ? val : 0.f);
        } else {
          if (col < ldp) Cb[(size_t)gr * ldp + col] = f2bf(val);          // xl (bf16 gather table)
          else           Cf[(size_t)gr * ldp + (col - ldp)] = val;        // xr (f32)
        }
      }
    }
  }
}

// ---------------- fused GATv2: split-K flash softmax + defer-max, one BLOCK per dst ----------------
// acc/s is exact for ANY reference m (max-tracking is overflow control only), so the
// rescale path runs only when p > m + 8 (rare). Common path: 1 exp, 4 fma, no rescale.

template<int D>
__launch_bounds__(256)
__global__ void gat_fused(const ushort* __restrict__ xlb, const float* __restrict__ xrf,
                          const float* __restrict__ att, const float* __restrict__ bias,
                          const int* __restrict__ offsets, const int* __restrict__ srcs,
                          float* __restrict__ out_f32, ushort* __restrict__ out_bf16,
                          int n_valid) {
  constexpr int EPL = D / 64;     // dims per lane
  const int v    = blockIdx.x;
  const int tid  = threadIdx.x;
  const int lane = tid & 63;
  const int wave = tid >> 6;
  const int d0   = lane * EPL;

  if (v >= n_valid) {             // pad rows -> zero bf16 row
    if (out_bf16 && tid < D) out_bf16[(size_t)v * D + tid] = 0;
    return;
  }

  __shared__ float m_s[4];
  __shared__ float s_s[4];
  __shared__ float buf[4][D];

  float rv[EPL], av[EPL], acc[EPL];
  #pragma unroll
  for (int d = 0; d < EPL; d++) {
    rv[d]  = xrf[(size_t)v * D + d0 + d];
    av[d]  = att[d0 + d];
    acc[d] = 0.f;
  }

  const int beg = offsets[v], end = offsets[v + 1];
  float m = -INFINITY, s = 0.f;

  int k = beg + wave;
  ushort xnxt[EPL];
  if (k < end) {
    const int u0 = srcs[k];
    if constexpr (EPL == 4) *(ushort4*)xnxt = *(const ushort4*)(xlb + (size_t)u0 * D + d0);
    else                    *(ushort2*)xnxt = *(const ushort2*)(xlb + (size_t)u0 * D + d0);
  }

  for (; k < end; k += 4) {
    ushort xcur[EPL];
    #pragma unroll
    for (int d = 0; d < EPL; d++) xcur[d] = xnxt[d];

    const int kn = k + 4;
    if (kn < end) {                 // prefetch next edge in this wave's stride
      const int un = srcs[kn];
      if constexpr (EPL == 4) *(ushort4*)xnxt = *(const ushort4*)(xlb + (size_t)un * D + d0);
      else                    *(ushort2*)xnxt = *(const ushort2*)(xlb + (size_t)un * D + d0);
    }

    float xv[EPL], p = 0.f;
    #pragma unroll
    for (int d = 0; d < EPL; d++) {
      xv[d] = bf2f(xcur[d]);
      float t = xv[d] + rv[d];
      t = fmaxf(t, NEG_SLOPE * t);           // leaky_relu (slope 0.2 > 0)
      p = fmaf(t, av[d], p);
    }
    #pragma unroll
    for (int off = 32; off > 0; off >>= 1) p += __shfl_xor(p, off);

    if (p <= m + 8.f) {             // defer-max common path (wave-uniform branch)
      const float w = __expf(p - m);
      s += w;
      #pragma unroll
      for (int d = 0; d < EPL; d++) acc[d] = fmaf(w, xv[d], acc[d]);
    } else {                        // rescale to new reference (first edge lands here)
      const float cold = __expf(m - p);      // exp(-inf)=0 on first edge
      s = fmaf(s, cold, 1.f);
      #pragma unroll
      for (int d = 0; d < EPL; d++) acc[d] = fmaf(acc[d], cold, xv[d]);
      m = p;
    }
  }

  // ---- split-K merge across the 4 waves (exact for any per-wave reference m) ----
  if (lane == 0) m_s[wave] = m;
  __syncthreads();
  const float M = fmaxf(fmaxf(m_s[0], m_s[1]), fmaxf(m_s[2], m_s[3]));  // finite (>=1 edge)
  const float c = __expf(m - M);            // 0 for empty partials (m = -inf)
  if (lane == 0) s_s[wave] = s * c;
  #pragma unroll
  for (int d = 0; d < EPL; d++) buf[wave][d0 + d] = acc[d] * c;
  __syncthreads();

  if (tid < D) {
    const float stot = s_s[0] + s_s[1] + s_s[2] + s_s[3];
    const float val = (buf[0][tid] + buf[1][tid] + buf[2][tid] + buf[3][tid]) / stot + bias[tid];
    if (out_f32)  out_f32[(size_t)v * D + tid] = val;
    if (out_bf16) out_bf16[(size_t)v * D + tid] = f2bf(val);
  }
}

// ---------------- launch ----------------

extern "C" void kernel_launch(void* const* d_in, const int* in_sizes, int n_in,
                              void* d_out, int out_size, void* d_ws, size_t ws_size,
                              hipStream_t stream) {
  const float* x     = (const float*)d_in[0];
  const int*   eidx  = (const int*)d_in[1];
  const float* Wpi   = (const float*)d_in[2];
  const float* bpi   = (const float*)d_in[3];
  const float* Wl1   = (const float*)d_in[4];
  const float* bl1   = (const float*)d_in[5];
  const float* Wr1   = (const float*)d_in[6];
  const float* br1   = (const float*)d_in[7];
  const float* att1  = (const float*)d_in[8];
  const float* bias1 = (const float*)d_in[9];
  const float* Wl2   = (const float*)d_in[10];
  const float* bl2   = (const float*)d_in[11];
  const float* Wr2   = (const float*)d_in[12];
  const float* br2   = (const float*)d_in[13];
  const float* att2  = (const float*)d_in[14];
  const float* bias2 = (const float*)d_in[15];
  const float* Wpo   = (const float*)d_in[16];
  const float* bpo   = (const float*)d_in[17];

  const int E    = in_sizes[1] / 2;
  const int n    = N_NODES;
  const int Etot = E + n;

  float* out_xhat = (float*)d_out;
  float* out_z    = (float*)d_out + (size_t)N_NODES * D_IN;

  // workspace carve-up
  char* wp = (char*)d_ws;
  auto alloc = [&](size_t bytes) { char* p = wp; wp += (bytes + 255) & ~(size_t)255; return p; };
  char* regionA = (char*)alloc((size_t)MPAD * KPAD_IN * 2);   // xb -> {xr1f,xl1b} -> {xr2f,xl2b}
  ushort* hb_db = (ushort*)alloc((size_t)MPAD * D0 * 2);      // hb then db
  ushort* zb    = (ushort*)alloc((size_t)MPAD * D1 * 2);
  int* counts  = (int*)alloc((size_t)n * 4);
  int* offsets = (int*)alloc((size_t)(n + 1) * 4);
  int* cursors = (int*)alloc((size_t)n * 4);
  int* srcs    = (int*)alloc((size_t)Etot * 4);
  ushort* Wpi_t = (ushort*)alloc((size_t)T_WPI * 2);
  ushort* W1cat = (ushort*)alloc((size_t)T_W1 * 2);
  ushort* W2cat = (ushort*)alloc((size_t)T_W2 * 2);
  ushort* Wpo_t = (ushort*)alloc((size_t)T_WPO * 2);
  float*  bcat1 = (float*)alloc(256 * 4);
  float*  bcat2 = (float*)alloc(512 * 4);

  ushort* xb   = (ushort*)regionA;
  // layer1 intermediates (alias regionA; xb dead by then)
  float*  xr1f = (float*)regionA;                                  // [MPAD][128] f32
  ushort* xl1b = (ushort*)(regionA + 8 * 1024 * 1024);             // [MPAD][128] bf16
  // layer2 intermediates (alias regionA; layer1 dead by then)
  float*  xr2f = (float*)regionA;                                  // [MPAD][256] f32
  ushort* xl2b = (ushort*)(regionA + 12 * 1024 * 1024);            // [MPAD][256] bf16
  ushort* hb   = hb_db;
  ushort* db   = hb_db;

  // prep (also zeroes counts) then CSR
  prep_all<<<(PREP_T + 255) / 256, 256, 0, stream>>>(
      x, xb, Wpi, Wl1, Wr1, Wl2, Wr2, Wpo, bl1, br1, bl2, br2,
      Wpi_t, W1cat, W2cat, Wpo_t, bcat1, bcat2, counts);
  const int tb = 256;
  count_kernel<<<(Etot + tb - 1) / tb, tb, 0, stream>>>(eidx, E, n, counts);
  scan_kernel<<<1, 1024, 0, stream>>>(counts, offsets, cursors, n);
  scatter_kernel<<<(Etot + tb - 1) / tb, tb, 0, stream>>>(eidx, E, n, cursors, srcs);

  // h = x @ Wpi + bpi  (bf16 out, pad rows zeroed)
  gemm_mfma<1><<<dim3(D0 / 64, MPAD / 64), 256, 0, stream>>>(
      xb, KPAD_IN, Wpi_t, KPAD_IN, bpi, nullptr, hb, D0, N_NODES, D0, KPAD_IN);
  // [xl1(bf16)|xr1(f32)] = h @ [Wl1|Wr1] + [bl1|br1]  (split epilogue, NL=128)
  gemm_mfma<2><<<dim3(256 / 64, MPAD / 64), 256, 0, stream>>>(
      hb, D0, W1cat, D0, bcat1, xr1f, xl1b, D1, N_NODES, 256, D0);
  // GAT1 (fused, block per node) -> out_z (f32) + zb (bf16 padded)
  gat_fused<D1><<<MPAD, 256, 0, stream>>>(xl1b, xr1f, att1, bias1,
                                          offsets, srcs, out_z, zb, N_NODES);
  // [xl2(bf16)|xr2(f32)] = z @ [Wl2|Wr2] + [bl2|br2]  (split epilogue, NL=256)
  gemm_mfma<2><<<dim3(512 / 64, MPAD / 64), 256, 0, stream>>>(
      zb, D1, W2cat, D1, bcat2, xr2f, xl2b, D0, N_NODES, 512, D1);
  // GAT2 (fused, block per node) -> db (bf16 padded)
  gat_fused<D0><<<MPAD, 256, 0, stream>>>(xl2b, xr2f, att2, bias2,
                                          offsets, srcs, nullptr, db, N_NODES);
  // x_hat = d @ Wpo + bpo  (f32 out, guarded)
  gemm_mfma<0><<<dim3(NPAD_OUT / 64, MPAD / 64), 256, 0, stream>>>(
      db, D0, Wpo_t, D0, bpo, out_xhat, nullptr, D_IN, N_NODES, D_IN, D0);
}

// Round 10
// 307.435 us; speedup vs baseline: 1.1318x; 1.0485x over previous
//
#include <hip/hip_runtime.h>
#include <math.h>

#define N_NODES 10000
#define MPAD    10112   // 158 * 64
#define D_IN    1000
#define KPAD_IN 1024
#define D0      256
#define D1      128
#define NPAD_OUT 1024
#define NEG_SLOPE 0.2f

typedef __attribute__((ext_vector_type(8))) short short8;
typedef __attribute__((ext_vector_type(4))) float f32x4;

__device__ __forceinline__ ushort f2bf(float f) {
  union { float f; unsigned u; } c; c.f = f;
  unsigned r = c.u + 0x7FFF + ((c.u >> 16) & 1);   // RNE
  return (ushort)(r >> 16);
}
__device__ __forceinline__ float bf2f(ushort b) {
  union { unsigned u; float f; } c; c.u = ((unsigned)b) << 16;
  return c.f;
}

// ---------------- CSR build ----------------

__global__ void count_kernel(const int* __restrict__ idx, int E, int n, int* __restrict__ counts) {
  int k = blockIdx.x * blockDim.x + threadIdx.x;
  int tot = E + n;
  if (k >= tot) return;
  int dst = (k < E) ? idx[E + k] : (k - E);   // self-loops appended
  atomicAdd(&counts[dst], 1);
}

__global__ void scan_kernel(const int* __restrict__ counts, int* __restrict__ offsets,
                            int* __restrict__ cursors, int n) {
  __shared__ int tsum[1024];
  int tid = threadIdx.x;
  int per = (n + 1023) / 1024;
  int start = tid * per;
  int end = start + per; if (end > n) end = n;
  int s = 0;
  for (int i = start; i < end; i++) s += counts[i];
  tsum[tid] = s;
  __syncthreads();
  for (int off = 1; off < 1024; off <<= 1) {
    int v = (tid >= off) ? tsum[tid - off] : 0;
    __syncthreads();
    if (tid >= off) tsum[tid] += v;
    __syncthreads();
  }
  int run = (tid == 0) ? 0 : tsum[tid - 1];
  for (int i = start; i < end; i++) {
    offsets[i] = run; cursors[i] = run;
    run += counts[i];
  }
  if (tid == 1023) offsets[n] = tsum[1023];
}

__global__ void scatter_kernel(const int* __restrict__ idx, int E, int n,
                               int* __restrict__ cursors, int* __restrict__ srcs) {
  int k = blockIdx.x * blockDim.x + threadIdx.x;
  int tot = E + n;
  if (k >= tot) return;
  int src, dst;
  if (k < E) { src = idx[k]; dst = idx[E + k]; }
  else       { src = k - E;  dst = src; }
  int pos = atomicAdd(&cursors[dst], 1);
  srcs[pos] = src;
}

// ---------------- fused prep: conv_x + all weight transposes + biases + zero counts ----------------

#define T_WPI   (256 * 1024)
#define T_W1    (256 * 256)
#define T_W2    (512 * 128)
#define T_WPO   (1024 * 256)
#define OFF_W1  T_WPI
#define OFF_W2  (OFF_W1 + T_W1)
#define OFF_WPO (OFF_W2 + T_W2)
#define OFF_B   (OFF_WPO + T_WPO)
#define T_ALL   (OFF_B + 768)
#define CONV_T  (MPAD * 256)         // threads, 4 elems each
#define PREP_T  (CONV_T + T_ALL + N_NODES)

__global__ void prep_all(const float* __restrict__ x, ushort* __restrict__ xb,
                         const float* __restrict__ Wpi,
                         const float* __restrict__ Wl1, const float* __restrict__ Wr1,
                         const float* __restrict__ Wl2, const float* __restrict__ Wr2,
                         const float* __restrict__ Wpo,
                         const float* __restrict__ bl1, const float* __restrict__ br1,
                         const float* __restrict__ bl2, const float* __restrict__ br2,
                         ushort* __restrict__ Wpi_t, ushort* __restrict__ W1cat,
                         ushort* __restrict__ W2cat, ushort* __restrict__ Wpo_t,
                         float* __restrict__ bcat1, float* __restrict__ bcat2,
                         int* __restrict__ counts) {
  int idx = blockIdx.x * 256 + threadIdx.x;
  if (idx < CONV_T) {                       // xb[r][k]: bf16(x) zero-padded, 4 elems/thread
    int r = idx >> 8, k4 = (idx & 255) * 4;
    ushort4 o = {0, 0, 0, 0};
    if (r < N_NODES && k4 < D_IN) {
      float4 v = *(const float4*)(x + (size_t)r * D_IN + k4);
      o.x = f2bf(v.x); o.y = f2bf(v.y); o.z = f2bf(v.z); o.w = f2bf(v.w);
    }
    *(ushort4*)(xb + (size_t)idx * 4) = o;
    return;
  }
  int j = idx - CONV_T;
  if (j < OFF_W1) {                         // Wpi_t [256][1024] <- Wpi [1000][256]
    int n = j >> 10, k = j & 1023;
    Wpi_t[j] = f2bf((k < 1000) ? Wpi[(size_t)k * 256 + n] : 0.f);
  } else if (j < OFF_W2) {                  // W1cat [256][256] <- Wl1|Wr1 [256][128]
    int q = j - OFF_W1, n = q >> 8, k = q & 255;
    float v = (n < 128) ? Wl1[k * 128 + n] : Wr1[k * 128 + (n - 128)];
    W1cat[q] = f2bf(v);
  } else if (j < OFF_WPO) {                 // W2cat [512][128] <- Wl2|Wr2 [128][256]
    int q = j - OFF_W2, n = q >> 7, k = q & 127;
    float v = (n < 256) ? Wl2[k * 256 + n] : Wr2[k * 256 + (n - 256)];
    W2cat[q] = f2bf(v);
  } else if (j < OFF_B) {                   // Wpo_t [1024][256] <- Wpo [256][1000]
    int q = j - OFF_WPO, n = q >> 8, k = q & 255;
    Wpo_t[q] = f2bf((n < 1000) ? Wpo[(size_t)k * 1000 + n] : 0.f);
  } else if (j < T_ALL) {
    int q = j - OFF_B;
    if (q < 128)      bcat1[q] = bl1[q];
    else if (q < 256) bcat1[q] = br1[q - 128];
    else if (q < 512) bcat2[q - 256] = bl2[q - 256];
    else              bcat2[q - 256] = br2[q - 512];
  } else {
    int q = j - T_ALL;
    if (q < N_NODES) counts[q] = 0;
  }
}

// ---------------- bf16 MFMA GEMM, 64x64 tile ----------------

template<int MODE>
__launch_bounds__(256)
__global__ void gemm_mfma(const ushort* __restrict__ A, int lda,
                          const ushort* __restrict__ Bt, int ldb,
                          const float* __restrict__ bias,
                          float* __restrict__ Cf, ushort* __restrict__ Cb, int ldp,
                          int M_valid, int N_valid, int K) {
  constexpr int BK = 32;
  __shared__ ushort As[64 * BK];   // 4 KB
  __shared__ ushort Bs[64 * BK];
  const int tid  = threadIdx.x;
  const int lane = tid & 63, wave = tid >> 6;
  const int wr = wave >> 1, wc = wave & 1;
  const int bm = blockIdx.y * 64, bn = blockIdx.x * 64;
  const int r16 = lane & 15, kb = lane >> 4;

  f32x4 acc[2][2] = {};

  const int srow = tid >> 2;          // 0..63
  const int scol = (tid & 3) * 8;     // ushort elems (16B)
  const ushort* Ag = A  + (size_t)(bm + srow) * lda + scol;
  const ushort* Bg = Bt + (size_t)(bn + srow) * ldb + scol;

  for (int k0 = 0; k0 < K; k0 += BK) {
    __builtin_amdgcn_global_load_lds((const __attribute__((address_space(1))) void*)(Ag + k0),
                                     (__attribute__((address_space(3))) void*)(As + tid * 8), 16, 0, 0);
    __builtin_amdgcn_global_load_lds((const __attribute__((address_space(1))) void*)(Bg + k0),
                                     (__attribute__((address_space(3))) void*)(Bs + tid * 8), 16, 0, 0);
    __syncthreads();

    short8 af[2], bfr[2];
    #pragma unroll
    for (int mi = 0; mi < 2; mi++)
      af[mi] = *(const short8*)(As + ((wr * 32 + mi * 16 + r16) * BK + kb * 8));
    #pragma unroll
    for (int ni = 0; ni < 2; ni++)
      bfr[ni] = *(const short8*)(Bs + ((wc * 32 + ni * 16 + r16) * BK + kb * 8));
    #pragma unroll
    for (int mi = 0; mi < 2; mi++)
      #pragma unroll
      for (int ni = 0; ni < 2; ni++)
        acc[mi][ni] = __builtin_amdgcn_mfma_f32_16x16x32_bf16(af[mi], bfr[ni], acc[mi][ni], 0, 0, 0);
    __syncthreads();
  }

  #pragma unroll
  for (int mi = 0; mi < 2; mi++) {
    const int row = bm + wr * 32 + mi * 16 + (lane >> 4) * 4;
    #pragma unroll
    for (int ni = 0; ni < 2; ni++) {
      const int col = bn + wc * 32 + ni * 16 + r16;
      const float bv = (col < N_valid) ? bias[col] : 0.f;
      #pragma unroll
      for (int r = 0; r < 4; r++) {
        const int gr = row + r;
        const float val = acc[mi][ni][r] + bv;
        if constexpr (MODE == 0) {
          if (gr < M_valid && col < N_valid) Cf[(size_t)gr * ldp + col] = val;
        } else if constexpr (MODE == 1) {
          Cb[(size_t)gr * ldp + col] = f2bf(gr < M_valid ? val : 0.f);
        } else {
          if (col < ldp) Cb[(size_t)gr * ldp + col] = f2bf(val);          // xl (bf16 gather table)
          else           Cf[(size_t)gr * ldp + (col - ldp)] = val;        // xr (f32)
        }
      }
    }
  }
}

// ---------------- fused GATv2: G-lane-group flash softmax, one BLOCK per dst ----------------
// G = D/16 lanes per edge (16 dims/lane in two coalesced halves). One wave processes
// 64/G edges per instruction batch -> shfl-reduce is log2(G) steps shared across the
// batch; serial chain per edge cut ~3.5x vs 64-lane reduce. Branchless online softmax
// per group (reference m is arbitrary => exact), block merge via split-K in LDS.

template<int D>
__launch_bounds__(256)
__global__ void gat_fused(const ushort* __restrict__ xlb, const float* __restrict__ xrf,
                          const float* __restrict__ att, const float* __restrict__ bias,
                          const int* __restrict__ offsets, const int* __restrict__ srcs,
                          float* __restrict__ out_f32, ushort* __restrict__ out_bf16,
                          int n_valid) {
  constexpr int G    = D / 16;            // lanes per group
  constexpr int LOGG = (D == 256) ? 4 : 3;
  constexpr int NGW  = 64 / G;            // groups per wave
  constexpr int NG   = 4 * NGW;           // groups per block
  constexpr int H    = D / 2;             // second-half dim offset

  const int v    = blockIdx.x;
  const int tid  = threadIdx.x;
  const int lane = tid & 63;
  const int wave = tid >> 6;
  const int sub  = lane & (G - 1);
  const int grp  = wave * NGW + (lane >> LOGG);
  const int d0   = sub * 8;               // dims [d0,d0+8) and [H+d0,H+d0+8)

  if (v >= n_valid) {                     // pad rows -> zero bf16 row
    if (out_bf16 && tid < D) out_bf16[(size_t)v * D + tid] = 0;
    return;
  }

  __shared__ float m_s[NG];
  __shared__ float s_s[NG];
  __shared__ float buf[NG][D];

  float rv[16], av[16], acc[16];
  #pragma unroll
  for (int i = 0; i < 8; i++) {
    rv[i]     = xrf[(size_t)v * D + d0 + i];
    rv[8 + i] = xrf[(size_t)v * D + H + d0 + i];
    av[i]     = att[d0 + i];
    av[8 + i] = att[H + d0 + i];
    acc[i] = 0.f; acc[8 + i] = 0.f;
  }

  const int beg = offsets[v], end = offsets[v + 1];
  float m = -1e30f, s = 0.f;

  int k = beg + grp;
  ushort xn[16];
  {
    const int ks = (k < end) ? k : beg;
    const int u  = srcs[ks];
    *(short8*)(xn)     = *(const short8*)(xlb + (size_t)u * D + d0);
    *(short8*)(xn + 8) = *(const short8*)(xlb + (size_t)u * D + H + d0);
  }

  const int iters = (end - beg + NG - 1) / NG;   // block-uniform
  for (int it = 0; it < iters; it++, k += NG) {
    const bool valid = (k < end);
    ushort xc[16];
    #pragma unroll
    for (int i = 0; i < 16; i++) xc[i] = xn[i];

    {   // prefetch next batch's row
      const int kn = k + NG;
      const int ks = (kn < end) ? kn : beg;
      const int u  = srcs[ks];
      *(short8*)(xn)     = *(const short8*)(xlb + (size_t)u * D + d0);
      *(short8*)(xn + 8) = *(const short8*)(xlb + (size_t)u * D + H + d0);
    }

    float xv[16];
    float p0 = 0.f, p1 = 0.f, p2 = 0.f, p3 = 0.f;
    #pragma unroll
    for (int i = 0; i < 4; i++) {
      float t;
      xv[i]      = bf2f(xc[i]);      t = xv[i]      + rv[i];      t = fmaxf(t, NEG_SLOPE * t); p0 = fmaf(t, av[i], p0);
      xv[4 + i]  = bf2f(xc[4 + i]);  t = xv[4 + i]  + rv[4 + i];  t = fmaxf(t, NEG_SLOPE * t); p1 = fmaf(t, av[4 + i], p1);
      xv[8 + i]  = bf2f(xc[8 + i]);  t = xv[8 + i]  + rv[8 + i];  t = fmaxf(t, NEG_SLOPE * t); p2 = fmaf(t, av[8 + i], p2);
      xv[12 + i] = bf2f(xc[12 + i]); t = xv[12 + i] + rv[12 + i]; t = fmaxf(t, NEG_SLOPE * t); p3 = fmaf(t, av[12 + i], p3);
    }
    float p = (p0 + p1) + (p2 + p3);
    #pragma unroll
    for (int off = G / 2; off > 0; off >>= 1) p += __shfl_xor(p, off);

    const float m2   = valid ? fmaxf(m, p) : m;
    const float cold = __expf(m - m2);          // ==1 when invalid or m unchanged
    const float w    = valid ? __expf(p - m2) : 0.f;
    s = fmaf(s, cold, w);
    #pragma unroll
    for (int d = 0; d < 16; d++) acc[d] = fmaf(acc[d], cold, w * xv[d]);
    m = m2;
  }

  // ---- split-K merge across the NG groups (exact for any per-group reference m) ----
  if (sub == 0) m_s[grp] = m;
  __syncthreads();
  float M = m_s[0];
  #pragma unroll
  for (int g = 1; g < NG; g++) M = fmaxf(M, m_s[g]);
  const float c = __expf(m - M);                // 0 for empty groups
  if (sub == 0) s_s[grp] = s * c;
  #pragma unroll
  for (int i = 0; i < 8; i++) {
    buf[grp][d0 + i]     = acc[i] * c;
    buf[grp][H + d0 + i] = acc[8 + i] * c;
  }
  __syncthreads();

  if (tid < D) {
    float stot = 0.f, val = 0.f;
    #pragma unroll
    for (int g = 0; g < NG; g++) { stot += s_s[g]; val += buf[g][tid]; }
    val = val / stot + bias[tid];
    if (out_f32)  out_f32[(size_t)v * D + tid] = val;
    if (out_bf16) out_bf16[(size_t)v * D + tid] = f2bf(val);
  }
}

// ---------------- launch ----------------

extern "C" void kernel_launch(void* const* d_in, const int* in_sizes, int n_in,
                              void* d_out, int out_size, void* d_ws, size_t ws_size,
                              hipStream_t stream) {
  const float* x     = (const float*)d_in[0];
  const int*   eidx  = (const int*)d_in[1];
  const float* Wpi   = (const float*)d_in[2];
  const float* bpi   = (const float*)d_in[3];
  const float* Wl1   = (const float*)d_in[4];
  const float* bl1   = (const float*)d_in[5];
  const float* Wr1   = (const float*)d_in[6];
  const float* br1   = (const float*)d_in[7];
  const float* att1  = (const float*)d_in[8];
  const float* bias1 = (const float*)d_in[9];
  const float* Wl2   = (const float*)d_in[10];
  const float* bl2   = (const float*)d_in[11];
  const float* Wr2   = (const float*)d_in[12];
  const float* br2   = (const float*)d_in[13];
  const float* att2  = (const float*)d_in[14];
  const float* bias2 = (const float*)d_in[15];
  const float* Wpo   = (const float*)d_in[16];
  const float* bpo   = (const float*)d_in[17];

  const int E    = in_sizes[1] / 2;
  const int n    = N_NODES;
  const int Etot = E + n;

  float* out_xhat = (float*)d_out;
  float* out_z    = (float*)d_out + (size_t)N_NODES * D_IN;

  // workspace carve-up
  char* wp = (char*)d_ws;
  auto alloc = [&](size_t bytes) { char* p = wp; wp += (bytes + 255) & ~(size_t)255; return p; };
  char* regionA = (char*)alloc((size_t)MPAD * KPAD_IN * 2);   // xb -> {xr1f,xl1b} -> {xr2f,xl2b}
  ushort* hb_db = (ushort*)alloc((size_t)MPAD * D0 * 2);      // hb then db
  ushort* zb    = (ushort*)alloc((size_t)MPAD * D1 * 2);
  int* counts  = (int*)alloc((size_t)n * 4);
  int* offsets = (int*)alloc((size_t)(n + 1) * 4);
  int* cursors = (int*)alloc((size_t)n * 4);
  int* srcs    = (int*)alloc((size_t)Etot * 4);
  ushort* Wpi_t = (ushort*)alloc((size_t)T_WPI * 2);
  ushort* W1cat = (ushort*)alloc((size_t)T_W1 * 2);
  ushort* W2cat = (ushort*)alloc((size_t)T_W2 * 2);
  ushort* Wpo_t = (ushort*)alloc((size_t)T_WPO * 2);
  float*  bcat1 = (float*)alloc(256 * 4);
  float*  bcat2 = (float*)alloc(512 * 4);

  ushort* xb   = (ushort*)regionA;
  float*  xr1f = (float*)regionA;                                  // [MPAD][128] f32
  ushort* xl1b = (ushort*)(regionA + 8 * 1024 * 1024);             // [MPAD][128] bf16
  float*  xr2f = (float*)regionA;                                  // [MPAD][256] f32
  ushort* xl2b = (ushort*)(regionA + 12 * 1024 * 1024);            // [MPAD][256] bf16
  ushort* hb   = hb_db;
  ushort* db   = hb_db;

  // prep (also zeroes counts) then CSR
  prep_all<<<(PREP_T + 255) / 256, 256, 0, stream>>>(
      x, xb, Wpi, Wl1, Wr1, Wl2, Wr2, Wpo, bl1, br1, bl2, br2,
      Wpi_t, W1cat, W2cat, Wpo_t, bcat1, bcat2, counts);
  const int tb = 256;
  count_kernel<<<(Etot + tb - 1) / tb, tb, 0, stream>>>(eidx, E, n, counts);
  scan_kernel<<<1, 1024, 0, stream>>>(counts, offsets, cursors, n);
  scatter_kernel<<<(Etot + tb - 1) / tb, tb, 0, stream>>>(eidx, E, n, cursors, srcs);

  // h = x @ Wpi + bpi  (bf16 out, pad rows zeroed)
  gemm_mfma<1><<<dim3(D0 / 64, MPAD / 64), 256, 0, stream>>>(
      xb, KPAD_IN, Wpi_t, KPAD_IN, bpi, nullptr, hb, D0, N_NODES, D0, KPAD_IN);
  // [xl1(bf16)|xr1(f32)] = h @ [Wl1|Wr1] + [bl1|br1]  (split epilogue, NL=128)
  gemm_mfma<2><<<dim3(256 / 64, MPAD / 64), 256, 0, stream>>>(
      hb, D0, W1cat, D0, bcat1, xr1f, xl1b, D1, N_NODES, 256, D0);
  // GAT1 (fused, block per node) -> out_z (f32) + zb (bf16 padded)
  gat_fused<D1><<<MPAD, 256, 0, stream>>>(xl1b, xr1f, att1, bias1,
                                          offsets, srcs, out_z, zb, N_NODES);
  // [xl2(bf16)|xr2(f32)] = z @ [Wl2|Wr2] + [bl2|br2]  (split epilogue, NL=256)
  gemm_mfma<2><<<dim3(512 / 64, MPAD / 64), 256, 0, stream>>>(
      zb, D1, W2cat, D1, bcat2, xr2f, xl2b, D0, N_NODES, 512, D1);
  // GAT2 (fused, block per node) -> db (bf16 padded)
  gat_fused<D0><<<MPAD, 256, 0, stream>>>(xl2b, xr2f, att2, bias2,
                                          offsets, srcs, nullptr, db, N_NODES);
  // x_hat = d @ Wpo + bpo  (f32 out, guarded)
  gemm_mfma<0><<<dim3(NPAD_OUT / 64, MPAD / 64), 256, 0, stream>>>(
      db, D0, Wpo_t, D0, bpo, out_xhat, nullptr, D_IN, N_NODES, D_IN, D0);
}